// Round 5
// baseline (97.975 us; speedup 1.0000x reference)
//
#include <hip/hip_runtime.h>

// STFT magnitude via bf16 MFMA GEMM.
// Round 5: BARRIER-FREE main loop. Each wave privately stages its own 64
// basis rows (3-buffer, 4 gload_lds/step, wave-local vmcnt(4) proof), so the
// 4 waves free-run and LDS/MFMA pipes overlap. sX (frames) staged once +
// one prologue barrier. TT=192, wave tile 64M x 96N (10 reads : 24 MFMA).
// 1 block/CU (128 KiB LDS), ILP-based latency hiding.

#define FL   800
#define HOP  200
#define CUT  401
#define NS   8000000
#define NT   40001
#define KSTEPS 25            // 800/32

#define FT   64              // freq tile (M: 64 real + 64 imag rows)
#define TT   192             // frame tile (N)
#define TTILES 209           // ceil(40001/192)
#define SLICE_SH 40960       // sX shorts: 20 gload iters * 4096 B (need 39000)
#define XBN  8016000         // xb length in shorts
#define BB_OFF 16032000      // byte offset of bb in ws (= XBN*2)

typedef short short8 __attribute__((ext_vector_type(8)));
typedef float float4v __attribute__((ext_vector_type(4)));

#define GU32 const __attribute__((address_space(1))) unsigned int*
#define LU32 __attribute__((address_space(3))) unsigned int*

__device__ inline unsigned short f2bf(float f) {
    union { float f; unsigned u; } v; v.f = f;
    unsigned r = v.u + 0x7FFFu + ((v.u >> 16) & 1u);   // RNE
    return (unsigned short)(r >> 16);
}

// ---- prep 1: x (fp32) -> xb (bf16, reflect-padded by 400) ----
__global__ void prep_x(const float* __restrict__ x, short* __restrict__ xb) {
    const int n8 = XBN / 8;
    for (int j = blockIdx.x * blockDim.x + threadIdx.x; j < n8;
         j += gridDim.x * blockDim.x) {
        const int i = j * 8;
        const int s = i - 400;
        short8 o;
        if (s >= 0 && s + 7 < NS) {
            const float4v a = *reinterpret_cast<const float4v*>(x + s);
            const float4v b = *reinterpret_cast<const float4v*>(x + s + 4);
            o[0]=f2bf(a[0]); o[1]=f2bf(a[1]); o[2]=f2bf(a[2]); o[3]=f2bf(a[3]);
            o[4]=f2bf(b[0]); o[5]=f2bf(b[1]); o[6]=f2bf(b[2]); o[7]=f2bf(b[3]);
        } else {
            #pragma unroll
            for (int q = 0; q < 8; ++q) {
                int sq = s + q;
                if (sq < 0) sq = -sq;
                else if (sq >= NS) sq = 2 * NS - 2 - sq;
                o[q] = f2bf(x[sq]);
            }
        }
        *reinterpret_cast<short8*>(xb + i) = o;
    }
}

// ---- prep 2: basis (802x800 fp32) -> bb (896x800 bf16, zero pad rows) ----
__global__ void prep_b(const float* __restrict__ basis, short* __restrict__ bb) {
    const int nch = 896 * 100;
    for (int j = blockIdx.x * blockDim.x + threadIdx.x; j < nch;
         j += gridDim.x * blockDim.x) {
        const int row = j / 100;
        const int col = (j % 100) * 8;
        short8 o;
        int src = -1;
        if (row < CUT) src = row;
        else if (row >= 448 && row < 448 + CUT) src = row - 47;
        if (src >= 0) {
            const float* p = basis + (size_t)src * 800 + col;
            const float4v a = *reinterpret_cast<const float4v*>(p);
            const float4v b = *reinterpret_cast<const float4v*>(p + 4);
            o[0]=f2bf(a[0]); o[1]=f2bf(a[1]); o[2]=f2bf(a[2]); o[3]=f2bf(a[3]);
            o[4]=f2bf(b[0]); o[5]=f2bf(b[1]); o[6]=f2bf(b[2]); o[7]=f2bf(b[3]);
        } else {
            #pragma unroll
            for (int q = 0; q < 8; ++q) o[q] = 0;
        }
        *reinterpret_cast<short8*>(bb + (size_t)row * 800 + col) = o;
    }
}

#define MF(A, X, C) C = __builtin_amdgcn_mfma_f32_16x16x32_bf16((A), (X), (C), 0, 0, 0)

// One barrier-free pipeline step (KS = compile-time after unroll).
// FC = frags for step KS (in regs). FN <- frags for KS+1 (private sB + sX).
// Issues the wave's 4 gload_lds for KS+2; vmcnt(4) proves KS+1 landed.
#define BODY(KS, FC, FN)                                                        \
  {                                                                             \
    if ((KS) <= 22) {                                                           \
      short* ip_ = sBw + (((KS) + 2) % 3) * 2048 + lane * 8;                    \
      __builtin_amdgcn_global_load_lds((GU32)(b0 + ((KS)+2)*32), (LU32)(ip_),        16, 0, 0); \
      __builtin_amdgcn_global_load_lds((GU32)(b1 + ((KS)+2)*32), (LU32)(ip_ + 512),  16, 0, 0); \
      __builtin_amdgcn_global_load_lds((GU32)(b2 + ((KS)+2)*32), (LU32)(ip_ + 1024), 16, 0, 0); \
      __builtin_amdgcn_global_load_lds((GU32)(b3 + ((KS)+2)*32), (LU32)(ip_ + 1536), 16, 0, 0); \
      asm volatile("s_waitcnt vmcnt(4)" ::: "memory");                          \
    } else if ((KS) == 23) {                                                    \
      asm volatile("s_waitcnt vmcnt(0)" ::: "memory");                          \
    }                                                                           \
    if ((KS) <= 23) {                                                           \
      const short* nb_ = sBw + (((KS) + 1) % 3) * 2048;                         \
      FN[0] = *reinterpret_cast<const short8*>(nb_ + mo0);                      \
      FN[1] = *reinterpret_cast<const short8*>(nb_ + mo1);                      \
      FN[2] = *reinterpret_cast<const short8*>(nb_ + mo2);                      \
      FN[3] = *reinterpret_cast<const short8*>(nb_ + mo3);                      \
      FN[4] = *reinterpret_cast<const short8*>(&sX[xbase + 0*3200 + ((KS)+1)*32]); \
      FN[5] = *reinterpret_cast<const short8*>(&sX[xbase + 1*3200 + ((KS)+1)*32]); \
      FN[6] = *reinterpret_cast<const short8*>(&sX[xbase + 2*3200 + ((KS)+1)*32]); \
      FN[7] = *reinterpret_cast<const short8*>(&sX[xbase + 3*3200 + ((KS)+1)*32]); \
      FN[8] = *reinterpret_cast<const short8*>(&sX[xbase + 4*3200 + ((KS)+1)*32]); \
      FN[9] = *reinterpret_cast<const short8*>(&sX[xbase + 5*3200 + ((KS)+1)*32]); \
    }                                                                           \
    __builtin_amdgcn_s_setprio(1);                                              \
    MF(FC[0], FC[4], acc_r[0][0]); MF(FC[0], FC[5], acc_r[0][1]);               \
    MF(FC[0], FC[6], acc_r[0][2]); MF(FC[0], FC[7], acc_r[0][3]);               \
    MF(FC[0], FC[8], acc_r[0][4]); MF(FC[0], FC[9], acc_r[0][5]);               \
    MF(FC[1], FC[4], acc_r[1][0]); MF(FC[1], FC[5], acc_r[1][1]);               \
    MF(FC[1], FC[6], acc_r[1][2]); MF(FC[1], FC[7], acc_r[1][3]);               \
    MF(FC[1], FC[8], acc_r[1][4]); MF(FC[1], FC[9], acc_r[1][5]);               \
    MF(FC[2], FC[4], acc_i[0][0]); MF(FC[2], FC[5], acc_i[0][1]);               \
    MF(FC[2], FC[6], acc_i[0][2]); MF(FC[2], FC[7], acc_i[0][3]);               \
    MF(FC[2], FC[8], acc_i[0][4]); MF(FC[2], FC[9], acc_i[0][5]);               \
    MF(FC[3], FC[4], acc_i[1][0]); MF(FC[3], FC[5], acc_i[1][1]);               \
    MF(FC[3], FC[6], acc_i[1][2]); MF(FC[3], FC[7], acc_i[1][3]);               \
    MF(FC[3], FC[8], acc_i[1][4]); MF(FC[3], FC[9], acc_i[1][5]);               \
    __builtin_amdgcn_s_setprio(0);                                              \
  }

__global__ __launch_bounds__(256, 1)
void stft_mag_kernel(const short* __restrict__ xb,
                     const short* __restrict__ bb,
                     float* __restrict__ out) {
    __shared__ short sX[SLICE_SH];          // 81920 B, shared, read-only after prologue
    __shared__ short sB[4 * 3 * 2048];      // 49152 B: per-wave private 3-buffer

    const int tid = threadIdx.x;

    // ---- bijective XCD-chunked swizzle (nwg=1463), y(f)-fastest ----
    const int nwg = TTILES * 7;
    const int q = nwg >> 3, r = nwg & 7;
    const int bid = blockIdx.x;
    const int xcd = bid & 7, idx = bid >> 3;
    const int wgid = (xcd < r ? xcd * (q + 1) : r * (q + 1) + (xcd - r) * q) + idx;
    const int t0 = (wgid / 7) * TT;
    const int f0 = (wgid % 7) * FT;

    const int lane = tid & 63;
    const int wid  = tid >> 6;
    const int wm   = wid >> 1;       // 0..1 -> which 32 freqs
    const int wn   = wid & 1;        // 0..1 -> which 96 frames
    const int l15  = lane & 15;
    const int l4   = lane >> 4;

    short* sBw = sB + wid * (3 * 2048);     // this wave's private 3 buffers

    // ---- per-lane global base pointers for private sB staging ----
    // chunk c = inst*64 + lane; row = c>>2 (0..63: 0-31 real, 32-63 imag),
    // stored slot = c&3 holds global slot (c&3)^((row>>1)&3)  [involution]
    const short *b0, *b1, *b2, *b3;
    {
        const int c0 = lane,      r0_ = c0 >> 2;
        const int c1 = 64 + lane, r1_ = c1 >> 2;
        const int c2 = 128 + lane, r2_ = c2 >> 2;
        const int c3 = 192 + lane, r3_ = c3 >> 2;
        const int g0 = (r0_ < 32) ? (f0 + wm*32 + r0_) : (448 + f0 + wm*32 + (r0_ - 32));
        const int g1 = (r1_ < 32) ? (f0 + wm*32 + r1_) : (448 + f0 + wm*32 + (r1_ - 32));
        const int g2 = (r2_ < 32) ? (f0 + wm*32 + r2_) : (448 + f0 + wm*32 + (r2_ - 32));
        const int g3 = (r3_ < 32) ? (f0 + wm*32 + r3_) : (448 + f0 + wm*32 + (r3_ - 32));
        b0 = bb + (size_t)g0 * 800 + ((c0 & 3) ^ ((r0_ >> 1) & 3)) * 8;
        b1 = bb + (size_t)g1 * 800 + ((c1 & 3) ^ ((r1_ >> 1) & 3)) * 8;
        b2 = bb + (size_t)g2 * 800 + ((c2 & 3) ^ ((r2_ >> 1) & 3)) * 8;
        b3 = bb + (size_t)g3 * 800 + ((c3 & 3) ^ ((r3_ >> 1) & 3)) * 8;
    }

    // ---- prologue: issue sB buf0 (ks0), sX (20 loads, clamped), sB buf1 (ks1) ----
    {
        short* ip = sBw + lane * 8;
        __builtin_amdgcn_global_load_lds((GU32)(b0), (LU32)(ip),        16, 0, 0);
        __builtin_amdgcn_global_load_lds((GU32)(b1), (LU32)(ip + 512),  16, 0, 0);
        __builtin_amdgcn_global_load_lds((GU32)(b2), (LU32)(ip + 1024), 16, 0, 0);
        __builtin_amdgcn_global_load_lds((GU32)(b3), (LU32)(ip + 1536), 16, 0, 0);
    }
    {
        const int sx0 = t0 * HOP + tid * 8;
        short* dst = sX + tid * 8;
        #pragma unroll
        for (int it = 0; it < 20; ++it) {
            int off = sx0 + it * 2048;
            if (off > XBN - 8) off = XBN - 8;   // clamp: garbage cols masked at store
            __builtin_amdgcn_global_load_lds((GU32)(xb + off),
                                             (LU32)(dst + it * 2048), 16, 0, 0);
        }
    }
    {
        short* ip = sBw + 2048 + lane * 8;
        __builtin_amdgcn_global_load_lds((GU32)(b0 + 32), (LU32)(ip),        16, 0, 0);
        __builtin_amdgcn_global_load_lds((GU32)(b1 + 32), (LU32)(ip + 512),  16, 0, 0);
        __builtin_amdgcn_global_load_lds((GU32)(b2 + 32), (LU32)(ip + 1024), 16, 0, 0);
        __builtin_amdgcn_global_load_lds((GU32)(b3 + 32), (LU32)(ip + 1536), 16, 0, 0);
    }

    // ---- fragment LDS offsets ----
    // M-frag m reads private row m*16+l15, stored slot l4^((row>>1)&3)
    int mo0, mo1, mo2, mo3;
    {
        const int ra = 0  + l15, rb = 16 + l15, rc = 32 + l15, rd = 48 + l15;
        mo0 = ra * 32 + (l4 ^ ((ra >> 1) & 3)) * 8;
        mo1 = rb * 32 + (l4 ^ ((rb >> 1) & 3)) * 8;
        mo2 = rc * 32 + (l4 ^ ((rc >> 1) & 3)) * 8;
        mo3 = rd * 32 + (l4 ^ ((rd >> 1) & 3)) * 8;
    }
    const int xbase = (wn * 96 + l15) * HOP + l4 * 8;   // + ni*3200 + ks*32

    float4v acc_r[2][6] = {};
    float4v acc_i[2][6] = {};

    short8 FA[10], FB[10];

    // ---- wait own sB0+sX (sB1 still flying), then the ONLY barrier ----
    asm volatile("s_waitcnt vmcnt(4)" ::: "memory");
    __builtin_amdgcn_s_barrier();
    asm volatile("" ::: "memory");

    // read frags for ks=0 into FA
    FA[0] = *reinterpret_cast<const short8*>(sBw + mo0);
    FA[1] = *reinterpret_cast<const short8*>(sBw + mo1);
    FA[2] = *reinterpret_cast<const short8*>(sBw + mo2);
    FA[3] = *reinterpret_cast<const short8*>(sBw + mo3);
    FA[4] = *reinterpret_cast<const short8*>(&sX[xbase + 0*3200]);
    FA[5] = *reinterpret_cast<const short8*>(&sX[xbase + 1*3200]);
    FA[6] = *reinterpret_cast<const short8*>(&sX[xbase + 2*3200]);
    FA[7] = *reinterpret_cast<const short8*>(&sX[xbase + 3*3200]);
    FA[8] = *reinterpret_cast<const short8*>(&sX[xbase + 4*3200]);
    FA[9] = *reinterpret_cast<const short8*>(&sX[xbase + 5*3200]);

    // ---- barrier-free main pipeline: 25 steps ----
    #pragma unroll
    for (int j = 0; j < 12; ++j) {
        BODY(2*j,     FA, FB);
        BODY(2*j + 1, FB, FA);
    }
    BODY(24, FA, FB);

    // ---- epilogue: magnitude + coalesced stores ----
    #pragma unroll
    for (int mi = 0; mi < 2; ++mi) {
        #pragma unroll
        for (int rr = 0; rr < 4; ++rr) {
            const int f = f0 + wm * 32 + mi * 16 + l4 * 4 + rr;
            if (f >= CUT) continue;
            #pragma unroll
            for (int ni = 0; ni < 6; ++ni) {
                const int t = t0 + wn * 96 + ni * 16 + l15;
                if (t < NT) {
                    const float vr = (mi == 0 ? acc_r[0][ni][rr] : acc_r[1][ni][rr]);
                    const float vi = (mi == 0 ? acc_i[0][ni][rr] : acc_i[1][ni][rr]);
                    out[(size_t)f * NT + t] = sqrtf(vr * vr + vi * vi);
                }
            }
        }
    }
}

extern "C" void kernel_launch(void* const* d_in, const int* in_sizes, int n_in,
                              void* d_out, int out_size, void* d_ws, size_t ws_size,
                              hipStream_t stream) {
    const float* x     = (const float*)d_in[0];
    const float* basis = (const float*)d_in[1];
    float* out = (float*)d_out;

    short* xb = (short*)d_ws;
    short* bb = (short*)((char*)d_ws + BB_OFF);

    prep_x<<<2048, 256, 0, stream>>>(x, xb);
    prep_b<<<350, 256, 0, stream>>>(basis, bb);

    stft_mag_kernel<<<TTILES * 7, 256, 0, stream>>>(xb, bb, out);
}

// Round 7
// 77.720 us; speedup vs baseline: 1.2606x; 1.2606x over previous
//
#include <hip/hip_runtime.h>

// STFT magnitude via bf16 MFMA GEMM.
// Round 7: NO sB at all — basis A-fragments are loaded global->register
// (basis is L2-resident; 4 l4-lanes read one full 64B line). Register loads
// are compiler-tracked => no manual waitcnt, no barriers, no races: LDS holds
// only sX (read-only after one prologue barrier). 8 waves (2F x 4N), wave
// tile 32F x 96N (6 ds_read : 24 MFMA), TT=384, distance-1 reg prefetch.

#define FL   800
#define HOP  200
#define CUT  401
#define NS   8000000
#define NT   40001
#define KSTEPS 25            // 800/32

#define FT   64              // freq tile per block
#define TT   384             // frame tile per block
#define NTT  105             // ceil(40001/384)
#define SLICE_SH 77824       // sX shorts: 19 iters * 4096 (need 77400)
#define XBN  8016000         // xb length in shorts
#define BB_OFF 16032000      // byte offset of bb in ws (= XBN*2)

typedef short short8 __attribute__((ext_vector_type(8)));
typedef float float4v __attribute__((ext_vector_type(4)));

#define GU32 const __attribute__((address_space(1))) unsigned int*
#define LU32 __attribute__((address_space(3))) unsigned int*

__device__ inline unsigned short f2bf(float f) {
    union { float f; unsigned u; } v; v.f = f;
    unsigned r = v.u + 0x7FFFu + ((v.u >> 16) & 1u);   // RNE
    return (unsigned short)(r >> 16);
}

// ---- prep 1: x (fp32) -> xb (bf16, reflect-padded by 400) ----
__global__ void prep_x(const float* __restrict__ x, short* __restrict__ xb) {
    const int n8 = XBN / 8;
    for (int j = blockIdx.x * blockDim.x + threadIdx.x; j < n8;
         j += gridDim.x * blockDim.x) {
        const int i = j * 8;
        const int s = i - 400;
        short8 o;
        if (s >= 0 && s + 7 < NS) {
            const float4v a = *reinterpret_cast<const float4v*>(x + s);
            const float4v b = *reinterpret_cast<const float4v*>(x + s + 4);
            o[0]=f2bf(a[0]); o[1]=f2bf(a[1]); o[2]=f2bf(a[2]); o[3]=f2bf(a[3]);
            o[4]=f2bf(b[0]); o[5]=f2bf(b[1]); o[6]=f2bf(b[2]); o[7]=f2bf(b[3]);
        } else {
            #pragma unroll
            for (int q = 0; q < 8; ++q) {
                int sq = s + q;
                if (sq < 0) sq = -sq;
                else if (sq >= NS) sq = 2 * NS - 2 - sq;
                o[q] = f2bf(x[sq]);
            }
        }
        *reinterpret_cast<short8*>(xb + i) = o;
    }
}

// ---- prep 2: basis (802x800 fp32) -> bb (896x800 bf16, zero pad rows) ----
__global__ void prep_b(const float* __restrict__ basis, short* __restrict__ bb) {
    const int nch = 896 * 100;
    for (int j = blockIdx.x * blockDim.x + threadIdx.x; j < nch;
         j += gridDim.x * blockDim.x) {
        const int row = j / 100;
        const int col = (j % 100) * 8;
        short8 o;
        int src = -1;
        if (row < CUT) src = row;
        else if (row >= 448 && row < 448 + CUT) src = row - 47;
        if (src >= 0) {
            const float* p = basis + (size_t)src * 800 + col;
            const float4v a = *reinterpret_cast<const float4v*>(p);
            const float4v b = *reinterpret_cast<const float4v*>(p + 4);
            o[0]=f2bf(a[0]); o[1]=f2bf(a[1]); o[2]=f2bf(a[2]); o[3]=f2bf(a[3]);
            o[4]=f2bf(b[0]); o[5]=f2bf(b[1]); o[6]=f2bf(b[2]); o[7]=f2bf(b[3]);
        } else {
            #pragma unroll
            for (int q = 0; q < 8; ++q) o[q] = 0;
        }
        *reinterpret_cast<short8*>(bb + (size_t)row * 800 + col) = o;
    }
}

#define MF(A, X, C) C = __builtin_amdgcn_mfma_f32_16x16x32_bf16((A), (X), (C), 0, 0, 0)

// One pipeline step. CA/CX = current frags (step KS); NA/NX <- prefetch frags
// for step KS+1 (A: global->reg, compiler-tracked vmcnt; X: LDS->reg,
// compiler-tracked lgkmcnt). Then 24 MFMAs on the current registers.
#define BODY(KS, CA, CX, NA, NX)                                               \
  {                                                                            \
    if ((KS) < 24) {                                                           \
      NA[0] = *reinterpret_cast<const short8*>(pr0 + ((KS)+1)*32);             \
      NA[1] = *reinterpret_cast<const short8*>(pr1 + ((KS)+1)*32);             \
      NA[2] = *reinterpret_cast<const short8*>(pi0 + ((KS)+1)*32);             \
      NA[3] = *reinterpret_cast<const short8*>(pi1 + ((KS)+1)*32);             \
      NX[0] = *reinterpret_cast<const short8*>(&sX[xoff + 0*3200 + ((KS)+1)*32]); \
      NX[1] = *reinterpret_cast<const short8*>(&sX[xoff + 1*3200 + ((KS)+1)*32]); \
      NX[2] = *reinterpret_cast<const short8*>(&sX[xoff + 2*3200 + ((KS)+1)*32]); \
      NX[3] = *reinterpret_cast<const short8*>(&sX[xoff + 3*3200 + ((KS)+1)*32]); \
      NX[4] = *reinterpret_cast<const short8*>(&sX[xoff + 4*3200 + ((KS)+1)*32]); \
      NX[5] = *reinterpret_cast<const short8*>(&sX[xoff + 5*3200 + ((KS)+1)*32]); \
    }                                                                          \
    __builtin_amdgcn_s_setprio(1);                                             \
    MF(CA[0], CX[0], acc_r[0][0]); MF(CA[0], CX[1], acc_r[0][1]);              \
    MF(CA[0], CX[2], acc_r[0][2]); MF(CA[0], CX[3], acc_r[0][3]);              \
    MF(CA[0], CX[4], acc_r[0][4]); MF(CA[0], CX[5], acc_r[0][5]);              \
    MF(CA[1], CX[0], acc_r[1][0]); MF(CA[1], CX[1], acc_r[1][1]);              \
    MF(CA[1], CX[2], acc_r[1][2]); MF(CA[1], CX[3], acc_r[1][3]);              \
    MF(CA[1], CX[4], acc_r[1][4]); MF(CA[1], CX[5], acc_r[1][5]);              \
    MF(CA[2], CX[0], acc_i[0][0]); MF(CA[2], CX[1], acc_i[0][1]);              \
    MF(CA[2], CX[2], acc_i[0][2]); MF(CA[2], CX[3], acc_i[0][3]);              \
    MF(CA[2], CX[4], acc_i[0][4]); MF(CA[2], CX[5], acc_i[0][5]);              \
    MF(CA[3], CX[0], acc_i[1][0]); MF(CA[3], CX[1], acc_i[1][1]);              \
    MF(CA[3], CX[2], acc_i[1][2]); MF(CA[3], CX[3], acc_i[1][3]);              \
    MF(CA[3], CX[4], acc_i[1][4]); MF(CA[3], CX[5], acc_i[1][5]);              \
    __builtin_amdgcn_s_setprio(0);                                             \
  }

__global__ __launch_bounds__(512, 2)
void stft_mag_kernel(const short* __restrict__ xb,
                     const short* __restrict__ bb,
                     float* __restrict__ out) {
    __shared__ short sX[SLICE_SH];     // 155648 B — the only LDS

    const int tid = threadIdx.x;

    // ---- bijective XCD-chunked swizzle (nwg=735), f-fastest so the 7 blocks
    //      sharing one xb slice land on the same XCD's L2 ----
    const int nwg = NTT * 7;
    const int q = nwg >> 3, r = nwg & 7;
    const int bid = blockIdx.x;
    const int xcd = bid & 7, idx = bid >> 3;
    const int wgid = (xcd < r ? xcd * (q + 1) : r * (q + 1) + (xcd - r) * q) + idx;
    const int t0 = (wgid / 7) * TT;
    const int f0 = (wgid % 7) * FT;

    const int lane = tid & 63;
    const int wid  = tid >> 6;
    const int wm   = wid >> 2;       // 0..1 -> which 32 freqs
    const int wn   = wid & 3;        // 0..3 -> which 96 frames
    const int l15  = lane & 15;
    const int l4   = lane >> 4;

    // ---- stage sX: 19 x global_load_lds width-16, clamped tail ----
    {
        const int g0 = t0 * HOP + tid * 8;
        short* dst = sX + tid * 8;
        #pragma unroll
        for (int it = 0; it < 19; ++it) {
            int off = g0 + it * 4096;
            if (off > XBN - 8) off = XBN - 8;   // garbage cols masked at store
            __builtin_amdgcn_global_load_lds((GU32)(xb + off),
                                             (LU32)(dst + it * 4096), 16, 0, 0);
        }
    }

    // ---- A-fragment global base pointers (per lane, 64B-line friendly) ----
    const short* pr0 = bb + (size_t)(f0 + wm * 32 + l15) * 800 + l4 * 8;
    const short* pr1 = bb + (size_t)(f0 + wm * 32 + 16 + l15) * 800 + l4 * 8;
    const short* pi0 = pr0 + (size_t)448 * 800;
    const short* pi1 = pr1 + (size_t)448 * 800;

    const int xoff = (wn * 96 + l15) * HOP + l4 * 8;   // + ni*3200 + ks*32

    float4v acc_r[2][6] = {};
    float4v acc_i[2][6] = {};

    short8 FAa[4], FAx[6], FBa[4], FBx[6];

    // A frags for ks=0 (global->reg, independent of LDS)
    FAa[0] = *reinterpret_cast<const short8*>(pr0);
    FAa[1] = *reinterpret_cast<const short8*>(pr1);
    FAa[2] = *reinterpret_cast<const short8*>(pi0);
    FAa[3] = *reinterpret_cast<const short8*>(pi1);

    // sX landed -> the ONLY barrier
    asm volatile("s_waitcnt vmcnt(0)" ::: "memory");
    __builtin_amdgcn_s_barrier();
    asm volatile("" ::: "memory");

    // X frags for ks=0
    FAx[0] = *reinterpret_cast<const short8*>(&sX[xoff + 0*3200]);
    FAx[1] = *reinterpret_cast<const short8*>(&sX[xoff + 1*3200]);
    FAx[2] = *reinterpret_cast<const short8*>(&sX[xoff + 2*3200]);
    FAx[3] = *reinterpret_cast<const short8*>(&sX[xoff + 3*3200]);
    FAx[4] = *reinterpret_cast<const short8*>(&sX[xoff + 4*3200]);
    FAx[5] = *reinterpret_cast<const short8*>(&sX[xoff + 5*3200]);

    // ---- barrier-free main pipeline: 25 steps ----
    #pragma unroll
    for (int jj = 0; jj < 12; ++jj) {
        BODY(2*jj,     FAa, FAx, FBa, FBx);
        BODY(2*jj + 1, FBa, FBx, FAa, FAx);
    }
    BODY(24, FAa, FAx, FBa, FBx);

    // ---- epilogue: magnitude + coalesced stores ----
    #pragma unroll
    for (int mi = 0; mi < 2; ++mi) {
        #pragma unroll
        for (int rr = 0; rr < 4; ++rr) {
            const int f = f0 + wm * 32 + mi * 16 + l4 * 4 + rr;
            if (f >= CUT) continue;
            #pragma unroll
            for (int ni = 0; ni < 6; ++ni) {
                const int t = t0 + wn * 96 + ni * 16 + l15;
                if (t < NT) {
                    const float vr = (mi == 0 ? acc_r[0][ni][rr] : acc_r[1][ni][rr]);
                    const float vi = (mi == 0 ? acc_i[0][ni][rr] : acc_i[1][ni][rr]);
                    out[(size_t)f * NT + t] = sqrtf(vr * vr + vi * vi);
                }
            }
        }
    }
}

extern "C" void kernel_launch(void* const* d_in, const int* in_sizes, int n_in,
                              void* d_out, int out_size, void* d_ws, size_t ws_size,
                              hipStream_t stream) {
    const float* x     = (const float*)d_in[0];
    const float* basis = (const float*)d_in[1];
    float* out = (float*)d_out;

    short* xb = (short*)d_ws;
    short* bb = (short*)((char*)d_ws + BB_OFF);

    prep_x<<<2048, 256, 0, stream>>>(x, xb);
    prep_b<<<350, 256, 0, stream>>>(basis, bb);

    stft_mag_kernel<<<NTT * 7, 512, 0, stream>>>(xb, bb, out);
}